// Round 15
// baseline (210.431 us; speedup 1.0000x reference)
//
#include <hip/hip_runtime.h>

#define KNN 32
#define BLOCK 256
#define NSLOT 128
#define GC 64
#define NCELL (GC * GC)
#define XMIN (-4.5f)
#define INVCS (64.0f / 9.0f)
#define CAPW 224
#define TGT 64.0f
#define TMAX 160.0f  // > max possible d2 (~155): rad covers whole grid -> count = N

// ws layout (full path, 180224 B):
//   [0, 16384):        NSLOT slots x 16 f64   c=0..3: sum_y,sum_y2,sum_m,sum_m2; c=4..8: W,S1y,S2y,S1m,S2m
//   [16384, 32768):    cellarr[NCELL] int     counts -> exclusive starts -> (after scatter) cell END offsets
//   [32768, 131072):   sorted_xy[N] float2
//   [131072, 180224):  sorted_idx[N] int
// moran num_y = S1y - mu_y*S2y + mu_y^2*W  (mean-free expansion; exact in f64)

__device__ inline float bessel_i0f(float z) {
  if (z < 3.75f) {
    float u = z * z * (1.0f / (3.75f * 3.75f));
    return 1.0f + u * (3.5156229f + u * (3.0899424f + u * (1.2067492f +
                  u * (0.2659732f + u * (0.0360768f + u * 0.0045813f)))));
  } else {
    float w = 3.75f / z;
    float p = 0.39894228f + w * (0.01328592f + w * (0.00225319f + w * (-0.00157565f +
              w * (0.00916281f + w * (-0.02057706f + w * (0.02635537f +
              w * (-0.01647633f + w * 0.00392377f)))))));
    return __expf(z) * p * __frsqrt_rn(z);
  }
}

// d2-threshold with E[#points: d2<t] ~= TGT (noncentral chi^2; 16-pt midpoint, 2 fixed-point iters)
__device__ inline float knn_threshold(float qs, int N) {
  float t = fminf(fmaxf((2.0f * TGT / (float)N) * __expf(0.5f * qs), 1e-3f), 12.0f);
  float aq = sqrtf(qs);
#pragma unroll
  for (int nit = 0; nit < 2; ++nit) {
    float dt = t * (1.0f / 16.0f);
    float acc = 0.0f;
#pragma unroll
    for (int k = 0; k < 16; ++k) {
      float s = ((float)k + 0.5f) * dt;
      acc += __expf(-0.5f * s) * bessel_i0f(aq * sqrtf(s));
    }
    float E = 0.5f * (float)N * __expf(-0.5f * qs) * acc * dt;
    t = fminf(fmaxf(t * (TGT / fmaxf(E, 1.0f)), 1e-3f), 32.0f);
  }
  return t;
}

__device__ inline int cell_of(float v) {
  return min(max((int)((v - XMIN) * INVCS), 0), GC - 1);
}

// counts points per cell (if cellcnt != null) and accumulates global y/m sums into hashed slots
__global__ __launch_bounds__(BLOCK) void count_sums_kernel(const float4* __restrict__ x4,
                                                           const float* __restrict__ y,
                                                           const float* __restrict__ m,
                                                           int* cellcnt, double* __restrict__ ws,
                                                           int N) {
  int tid = threadIdx.x, lane = tid & 63, wid = tid >> 6;
  int j = blockIdx.x * BLOCK + tid;
  double sy = 0, sy2 = 0, sm = 0, sm2 = 0;
  if (j < N) {
    float4 p = x4[j];
    if (cellcnt) atomicAdd(&cellcnt[cell_of(p.y) * GC + cell_of(p.x)], 1);
    sy = (double)y[j]; sy2 = sy * sy;
    sm = (double)m[j]; sm2 = sm * sm;
  }
  for (int off = 32; off > 0; off >>= 1) {
    sy  += __shfl_down(sy, off, 64);
    sy2 += __shfl_down(sy2, off, 64);
    sm  += __shfl_down(sm, off, 64);
    sm2 += __shfl_down(sm2, off, 64);
  }
  __shared__ double red[4][4];
  if (lane == 0) { red[wid][0] = sy; red[wid][1] = sy2; red[wid][2] = sm; red[wid][3] = sm2; }
  __syncthreads();
  if (tid < 4) {
    double v = red[0][tid] + red[1][tid] + red[2][tid] + red[3][tid];
    atomicAdd(&ws[(blockIdx.x & (NSLOT - 1)) * 16 + tid], v);
  }
}

// exclusive scan of NCELL counts in place (one block, 16 cells/thread)
__global__ __launch_bounds__(BLOCK) void scan_kernel(int* cellarr) {
  __shared__ int wtot[4];
  int tid = threadIdx.x, lane = tid & 63, wid = tid >> 6;
  int base = tid * 16;
  int v[16];
  int tot = 0;
#pragma unroll
  for (int k = 0; k < 16; ++k) { v[k] = cellarr[base + k]; tot += v[k]; }
  int scan = tot;
  for (int off = 1; off < 64; off <<= 1) {
    int u = __shfl_up(scan, off, 64);
    if (lane >= off) scan += u;
  }
  if (lane == 63) wtot[wid] = scan;
  __syncthreads();
  int add = 0;
  for (int w = 0; w < wid; ++w) add += wtot[w];
  int excl = add + scan - tot;
#pragma unroll
  for (int k = 0; k < 16; ++k) { int c = v[k]; cellarr[base + k] = excl; excl += c; }
}

// scatter into sorted order; afterwards cellarr[c] == END offset of cell c
__global__ __launch_bounds__(BLOCK) void scatter_kernel(const float4* __restrict__ x4,
                                                        int* cellarr, float2* __restrict__ sxy,
                                                        int* __restrict__ sidx, int N) {
  int j = blockIdx.x * BLOCK + threadIdx.x;
  if (j < N) {
    float4 p = x4[j];
    int pos = atomicAdd(&cellarr[cell_of(p.y) * GC + cell_of(p.x)], 1);
    sxy[pos] = make_float2(p.x, p.y);
    sidx[pos] = j;
  }
}

// one block per cell; one wave per query; ring scan + exact-count verify + bisection settle
__global__ __launch_bounds__(BLOCK) void query_kernel(const int* __restrict__ cellend,
                                                      const float2* __restrict__ sxy,
                                                      const int* __restrict__ sidx,
                                                      const float* __restrict__ y,
                                                      const float* __restrict__ m,
                                                      double* __restrict__ ws, int N) {
  __shared__ unsigned long long s_wc[4][CAPW];
  __shared__ int s_wcount[4];
  __shared__ float s_seld[4][KNN];
  __shared__ int s_seli[4][KNN];
  __shared__ double s_part[4][5];

  const int cell = blockIdx.x;
  const int tid = threadIdx.x, lane = tid & 63, wid = tid >> 6;
  const int qlo = cell ? cellend[cell - 1] : 0;
  const int qhi = cellend[cell];
  if (qlo == qhi) return;  // uniform

  double pW = 0, pS1y = 0, pS2y = 0, pS1m = 0, pS2m = 0;

  for (int qi = qlo + wid; qi < qhi; qi += 4) {
    float2 q = sxy[qi];
    const int iq = sidx[qi];
    const float qx = q.x, qy = q.y, qs = qx * qx + qy * qy;
    float t = knn_threshold(qs, N);
    float tlo = 0.0f, thi = -1.0f;
    int C = 0;
    for (int att = 0; att < 16; ++att) {
      if (lane == 0) s_wcount[wid] = 0;  // wave-internal; DS ops in program order
      float rad = sqrtf(t);
      int cx0 = min(max((int)((qx - rad - XMIN) * INVCS), 0), GC - 1);
      int cx1 = min(max((int)((qx + rad - XMIN) * INVCS), 0), GC - 1);
      int cy0 = min(max((int)((qy - rad - XMIN) * INVCS), 0), GC - 1);
      int cy1 = min(max((int)((qy + rad - XMIN) * INVCS), 0), GC - 1);
      for (int cy = cy0; cy <= cy1; ++cy) {
        int rowbase = cy * GC;
        int p0 = (rowbase + cx0) ? cellend[rowbase + cx0 - 1] : 0;
        int p1 = cellend[rowbase + cx1];
        for (int p = p0 + lane; p < p1; p += 64) {
          float2 pt = sxy[p];
          float sqj = pt.x * pt.x + pt.y * pt.y;
          float dot = qx * pt.x + qy * pt.y;
          float d2 = fmaxf(qs + sqj - 2.0f * dot, 1e-30f);
          if (d2 < t) {
            int pos = atomicAdd(&s_wcount[wid], 1);
            if (pos < CAPW)
              s_wc[wid][pos] = (((unsigned long long)__float_as_uint(d2)) << 32) |
                               (unsigned long long)(unsigned)sidx[p];
          }
        }
      }
      C = s_wcount[wid];  // exact predicate count (counts past CAPW); uniform per wave
      if (C >= KNN && C <= CAPW) break;
      if (C < KNN) {
        tlo = t;
        t = (thi > 0.0f) ? sqrtf(tlo * thi)
                         : fminf(t * fminf(fmaxf(96.0f / (float)(C > 0 ? C : 1), 3.0f), 16.0f), TMAX);
      } else {
        thi = t;
        t = (tlo > 0.0f) ? sqrtf(tlo * thi) : t * fmaxf(64.0f / (float)C, 0.02f);
      }
    }
    if (C > CAPW) C = CAPW;

    // rank-canonical selection (ties -> smaller original idx, == top_k); wave-internal
    for (int c = lane; c < C; c += 64) {
      unsigned long long mine = s_wc[wid][c];
      int rank = 0;
      for (int qq = 0; qq < C; ++qq) rank += (s_wc[wid][qq] < mine) ? 1 : 0;
      if (rank < KNN) {
        s_seld[wid][rank] = __uint_as_float((unsigned)(mine >> 32));
        s_seli[wid][rank] = (int)(unsigned)(mine & 0xffffffffull);
      }
    }
    float w = 0, wy = 0, wm = 0;
    if (lane < KNN) {
      int idx = s_seli[wid][lane];
      float dist = sqrtf(s_seld[wid][lane]);  // == reference sqrt(max(d2,1e-30))
      w = expf(-0.1f * dist);
      wy = w * y[idx];
      wm = w * m[idx];
    }
    for (int off = 32; off > 0; off >>= 1) {
      w  += __shfl_down(w, off, 64);
      wy += __shfl_down(wy, off, 64);
      wm += __shfl_down(wm, off, 64);
    }
    if (lane == 0) {
      double yi = (double)y[iq], mi = (double)m[iq];
      pW += (double)w;
      pS1y += yi * (double)wy;
      pS2y += yi * (double)w + (double)wy;
      pS1m += mi * (double)wm;
      pS2m += mi * (double)w + (double)wm;
    }
  }
  if (lane == 0) {
    s_part[wid][0] = pW; s_part[wid][1] = pS1y; s_part[wid][2] = pS2y;
    s_part[wid][3] = pS1m; s_part[wid][4] = pS2m;
  }
  __syncthreads();
  if (tid < 5) {
    double val = s_part[0][tid] + s_part[1][tid] + s_part[2][tid] + s_part[3][tid];
    atomicAdd(&ws[(blockIdx.x & (NSLOT - 1)) * 16 + 4 + tid], val);
  }
}

// fallback (ws too small for grid): one wave per query, full N scan, same settle/rank/accumulate
__global__ __launch_bounds__(BLOCK) void knn_full_kernel(const float4* __restrict__ x4,
                                                         const float* __restrict__ y,
                                                         const float* __restrict__ m,
                                                         double* __restrict__ ws, int N) {
  __shared__ unsigned long long s_wc[4][CAPW];
  __shared__ int s_wcount[4];
  __shared__ float s_seld[4][KNN];
  __shared__ int s_seli[4][KNN];
  __shared__ double s_part[4][5];
  const int tid = threadIdx.x, lane = tid & 63, wid = tid >> 6;
  const int iq = blockIdx.x * 4 + wid;
  double pW = 0, pS1y = 0, pS2y = 0, pS1m = 0, pS2m = 0;
  if (iq < N) {
    float4 qv = x4[iq];
    const float qx = qv.x, qy = qv.y, qs = qx * qx + qy * qy;
    float t = knn_threshold(qs, N);
    float tlo = 0.0f, thi = -1.0f;
    int C = 0;
    for (int att = 0; att < 16; ++att) {
      if (lane == 0) s_wcount[wid] = 0;
      for (int j = lane; j < N; j += 64) {
        float4 pt = x4[j];
        float sqj = pt.x * pt.x + pt.y * pt.y;
        float dot = qx * pt.x + qy * pt.y;
        float d2 = fmaxf(qs + sqj - 2.0f * dot, 1e-30f);
        if (d2 < t) {
          int pos = atomicAdd(&s_wcount[wid], 1);
          if (pos < CAPW)
            s_wc[wid][pos] = (((unsigned long long)__float_as_uint(d2)) << 32) |
                             (unsigned long long)(unsigned)j;
        }
      }
      C = s_wcount[wid];
      if (C >= KNN && C <= CAPW) break;
      if (C < KNN) {
        tlo = t;
        t = (thi > 0.0f) ? sqrtf(tlo * thi)
                         : fminf(t * fminf(fmaxf(96.0f / (float)(C > 0 ? C : 1), 3.0f), 16.0f), TMAX);
      } else {
        thi = t;
        t = (tlo > 0.0f) ? sqrtf(tlo * thi) : t * fmaxf(64.0f / (float)C, 0.02f);
      }
    }
    if (C > CAPW) C = CAPW;
    for (int c = lane; c < C; c += 64) {
      unsigned long long mine = s_wc[wid][c];
      int rank = 0;
      for (int qq = 0; qq < C; ++qq) rank += (s_wc[wid][qq] < mine) ? 1 : 0;
      if (rank < KNN) {
        s_seld[wid][rank] = __uint_as_float((unsigned)(mine >> 32));
        s_seli[wid][rank] = (int)(unsigned)(mine & 0xffffffffull);
      }
    }
    float w = 0, wy = 0, wm = 0;
    if (lane < KNN) {
      int idx = s_seli[wid][lane];
      float dist = sqrtf(s_seld[wid][lane]);
      w = expf(-0.1f * dist);
      wy = w * y[idx];
      wm = w * m[idx];
    }
    for (int off = 32; off > 0; off >>= 1) {
      w  += __shfl_down(w, off, 64);
      wy += __shfl_down(wy, off, 64);
      wm += __shfl_down(wm, off, 64);
    }
    if (lane == 0) {
      double yi = (double)y[iq], mi = (double)m[iq];
      pW = (double)w;
      pS1y = yi * (double)wy;
      pS2y = yi * (double)w + (double)wy;
      pS1m = mi * (double)wm;
      pS2m = mi * (double)w + (double)wm;
    }
  }
  if (lane == 0) {
    s_part[wid][0] = pW; s_part[wid][1] = pS1y; s_part[wid][2] = pS2y;
    s_part[wid][3] = pS1m; s_part[wid][4] = pS2m;
  }
  __syncthreads();
  if (tid < 5) {
    double val = s_part[0][tid] + s_part[1][tid] + s_part[2][tid] + s_part[3][tid];
    atomicAdd(&ws[(blockIdx.x & (NSLOT - 1)) * 16 + 4 + tid], val);
  }
}

__global__ __launch_bounds__(128) void finalize_kernel(const double* __restrict__ ws,
                                                       float* __restrict__ out, int N) {
  __shared__ double part[2][9];
  int tid = threadIdx.x;  // 128 threads = NSLOT
  double v[9];
#pragma unroll
  for (int c = 0; c < 9; ++c) v[c] = ws[tid * 16 + c];
#pragma unroll
  for (int c = 0; c < 9; ++c)
    for (int off = 32; off > 0; off >>= 1) v[c] += __shfl_down(v[c], off, 64);
  if ((tid & 63) == 0)
#pragma unroll
    for (int c = 0; c < 9; ++c) part[tid >> 6][c] = v[c];
  __syncthreads();
  if (tid == 0) {
    double t[9];
#pragma unroll
    for (int c = 0; c < 9; ++c) t[c] = part[0][c] + part[1][c];
    double sy = t[0], sy2 = t[1], sm = t[2], sm2 = t[3];
    double W = t[4], S1y = t[5], S2y = t[6], S1m = t[7], S2m = t[8];
    double muy = sy / (double)N, mum = sm / (double)N;
    double deny = sy2 - sy * sy / (double)N;
    double denm = sm2 - sm * sm / (double)N;
    double numy = S1y - muy * S2y + muy * muy * W;
    double numm = S1m - mum * S2m + mum * mum * W;
    out[0] = (float)((double)N / W * numy / deny);
    out[1] = (float)((double)N / W * numm / denm);
  }
}

extern "C" void kernel_launch(void* const* d_in, const int* in_sizes, int n_in,
                              void* d_out, int out_size, void* d_ws, size_t ws_size,
                              hipStream_t stream) {
  const float4* x4 = (const float4*)d_in[0];  // (1, N, 4)
  const float* y   = (const float*)d_in[1];   // (1, N, 1)
  const float* mu  = (const float*)d_in[2];   // (1, N, 1)
  float* out = (float*)d_out;
  int N = in_sizes[1];  // 12288
  double* ws = (double*)d_ws;

  const size_t slots_b = (size_t)NSLOT * 16 * sizeof(double);          // 16384
  const size_t cells_b = (size_t)NCELL * sizeof(int);                  // 16384
  const size_t sxy_off = slots_b + cells_b;                            // 32768
  const size_t sidx_off = sxy_off + (size_t)N * sizeof(float2);        // 131072
  const size_t full_need = sidx_off + (size_t)N * sizeof(int);         // 180224

  int nblk = (N + BLOCK - 1) / BLOCK;
  if (ws_size >= full_need) {
    int* cellarr = (int*)((char*)d_ws + slots_b);
    float2* sxy = (float2*)((char*)d_ws + sxy_off);
    int* sidx = (int*)((char*)d_ws + sidx_off);
    hipMemsetAsync(d_ws, 0, slots_b + cells_b, stream);
    count_sums_kernel<<<nblk, BLOCK, 0, stream>>>(x4, y, mu, cellarr, ws, N);
    scan_kernel<<<1, BLOCK, 0, stream>>>(cellarr);
    scatter_kernel<<<nblk, BLOCK, 0, stream>>>(x4, cellarr, sxy, sidx, N);
    query_kernel<<<NCELL, BLOCK, 0, stream>>>(cellarr, sxy, sidx, y, mu, ws, N);
  } else {
    hipMemsetAsync(d_ws, 0, slots_b, stream);
    count_sums_kernel<<<nblk, BLOCK, 0, stream>>>(x4, y, mu, nullptr, ws, N);
    knn_full_kernel<<<(N + 3) / 4, BLOCK, 0, stream>>>(x4, y, mu, ws, N);
  }
  finalize_kernel<<<1, 128, 0, stream>>>(ws, out, N);
}

// Round 16
// 82.483 us; speedup vs baseline: 2.5512x; 2.5512x over previous
//
#include <hip/hip_runtime.h>

#define KNN 32
#define BLOCK 256
#define NSLOT 128
#define GC 64
#define NCELL (GC * GC)
#define XMIN (-4.5f)
#define INVCS (64.0f / 9.0f)
#define CAPW 224
#define TGT 64.0f
#define TMAX 160.0f  // > max possible d2 (~155): rad covers whole grid -> count = N

// ws layout (full path, 180224 B):
//   [0, 16384):        NSLOT slots x 16 f64   c=0..3: sum_y,sum_y2,sum_m,sum_m2; c=4..8: W,S1y,S2y,S1m,S2m
//   [16384, 32768):    cellarr[NCELL] int     counts -> exclusive starts -> (after scatter) cell END offsets
//   [32768, 131072):   sorted_xy[N] float2
//   [131072, 180224):  sorted_idx[N] int
// moran num_y = S1y - mu_y*S2y + mu_y^2*W  (mean-free expansion; exact in f64)

__device__ inline float bessel_i0f(float z) {
  if (z < 3.75f) {
    float u = z * z * (1.0f / (3.75f * 3.75f));
    return 1.0f + u * (3.5156229f + u * (3.0899424f + u * (1.2067492f +
                  u * (0.2659732f + u * (0.0360768f + u * 0.0045813f)))));
  } else {
    float w = 3.75f / z;
    float p = 0.39894228f + w * (0.01328592f + w * (0.00225319f + w * (-0.00157565f +
              w * (0.00916281f + w * (-0.02057706f + w * (0.02635537f +
              w * (-0.01647633f + w * 0.00392377f)))))));
    return __expf(z) * p * __frsqrt_rn(z);
  }
}

// d2-threshold with E[#points: d2<t] ~= TGT (noncentral chi^2; 16-pt midpoint, 2 fixed-point iters)
__device__ inline float knn_threshold(float qs, int N) {
  float t = fminf(fmaxf((2.0f * TGT / (float)N) * __expf(0.5f * qs), 1e-3f), 12.0f);
  float aq = sqrtf(qs);
#pragma unroll
  for (int nit = 0; nit < 2; ++nit) {
    float dt = t * (1.0f / 16.0f);
    float acc = 0.0f;
#pragma unroll
    for (int k = 0; k < 16; ++k) {
      float s = ((float)k + 0.5f) * dt;
      acc += __expf(-0.5f * s) * bessel_i0f(aq * sqrtf(s));
    }
    float E = 0.5f * (float)N * __expf(-0.5f * qs) * acc * dt;
    t = fminf(fmaxf(t * (TGT / fmaxf(E, 1.0f)), 1e-3f), 32.0f);
  }
  return t;
}

__device__ inline int cell_of(float v) {
  return min(max((int)((v - XMIN) * INVCS), 0), GC - 1);
}

// counts points per cell (if cellcnt != null) and accumulates global y/m sums into hashed slots
__global__ __launch_bounds__(BLOCK) void count_sums_kernel(const float4* __restrict__ x4,
                                                           const float* __restrict__ y,
                                                           const float* __restrict__ m,
                                                           int* cellcnt, double* __restrict__ ws,
                                                           int N) {
  int tid = threadIdx.x, lane = tid & 63, wid = tid >> 6;
  int j = blockIdx.x * BLOCK + tid;
  double sy = 0, sy2 = 0, sm = 0, sm2 = 0;
  if (j < N) {
    float4 p = x4[j];
    if (cellcnt) atomicAdd(&cellcnt[cell_of(p.y) * GC + cell_of(p.x)], 1);
    sy = (double)y[j]; sy2 = sy * sy;
    sm = (double)m[j]; sm2 = sm * sm;
  }
  for (int off = 32; off > 0; off >>= 1) {
    sy  += __shfl_down(sy, off, 64);
    sy2 += __shfl_down(sy2, off, 64);
    sm  += __shfl_down(sm, off, 64);
    sm2 += __shfl_down(sm2, off, 64);
  }
  __shared__ double red[4][4];
  if (lane == 0) { red[wid][0] = sy; red[wid][1] = sy2; red[wid][2] = sm; red[wid][3] = sm2; }
  __syncthreads();
  if (tid < 4) {
    double v = red[0][tid] + red[1][tid] + red[2][tid] + red[3][tid];
    atomicAdd(&ws[(blockIdx.x & (NSLOT - 1)) * 16 + tid], v);
  }
}

// exclusive scan of NCELL counts in place (one block, 16 cells/thread)
__global__ __launch_bounds__(BLOCK) void scan_kernel(int* cellarr) {
  __shared__ int wtot[4];
  int tid = threadIdx.x, lane = tid & 63, wid = tid >> 6;
  int base = tid * 16;
  int v[16];
  int tot = 0;
#pragma unroll
  for (int k = 0; k < 16; ++k) { v[k] = cellarr[base + k]; tot += v[k]; }
  int scan = tot;
  for (int off = 1; off < 64; off <<= 1) {
    int u = __shfl_up(scan, off, 64);
    if (lane >= off) scan += u;
  }
  if (lane == 63) wtot[wid] = scan;
  __syncthreads();
  int add = 0;
  for (int w = 0; w < wid; ++w) add += wtot[w];
  int excl = add + scan - tot;
#pragma unroll
  for (int k = 0; k < 16; ++k) { int c = v[k]; cellarr[base + k] = excl; excl += c; }
}

// scatter into sorted order; afterwards cellarr[c] == END offset of cell c
__global__ __launch_bounds__(BLOCK) void scatter_kernel(const float4* __restrict__ x4,
                                                        int* cellarr, float2* __restrict__ sxy,
                                                        int* __restrict__ sidx, int N) {
  int j = blockIdx.x * BLOCK + threadIdx.x;
  if (j < N) {
    float4 p = x4[j];
    int pos = atomicAdd(&cellarr[cell_of(p.y) * GC + cell_of(p.x)], 1);
    sxy[pos] = make_float2(p.x, p.y);
    sidx[pos] = j;
  }
}

// ONE WAVE PER QUERY (sorted order -> uniform blocks + L2 locality); ring scan with
// early-exit on overshoot; exact-count verify + geometric-bisection settle.
__global__ __launch_bounds__(BLOCK) void query_kernel(const int* __restrict__ cellend,
                                                      const float2* __restrict__ sxy,
                                                      const int* __restrict__ sidx,
                                                      const float* __restrict__ y,
                                                      const float* __restrict__ m,
                                                      double* __restrict__ ws, int N) {
  __shared__ unsigned long long s_wc[4][CAPW];
  __shared__ int s_wcount[4];
  __shared__ float s_seld[4][KNN];
  __shared__ int s_seli[4][KNN];
  __shared__ double s_part[4][5];

  const int tid = threadIdx.x, lane = tid & 63, wid = tid >> 6;
  const int qi = blockIdx.x * 4 + wid;  // sorted-order query position (N divisible by 4)

  float2 q = sxy[qi];
  const int iq = sidx[qi];
  const float qx = q.x, qy = q.y, qs = qx * qx + qy * qy;
  float t = knn_threshold(qs, N);
  float tlo = 0.0f, thi = -1.0f;
  int C = 0;
  for (int att = 0; att < 24; ++att) {
    if (lane == 0) s_wcount[wid] = 0;  // wave-internal; DS ops in program order
    float rad = sqrtf(t);
    int cx0 = min(max((int)((qx - rad - XMIN) * INVCS), 0), GC - 1);
    int cx1 = min(max((int)((qx + rad - XMIN) * INVCS), 0), GC - 1);
    int cy0 = min(max((int)((qy - rad - XMIN) * INVCS), 0), GC - 1);
    int cy1 = min(max((int)((qy + rad - XMIN) * INVCS), 0), GC - 1);
    for (int cy = cy0; cy <= cy1; ++cy) {
      int rowbase = cy * GC;
      int p0 = (rowbase + cx0) ? cellend[rowbase + cx0 - 1] : 0;
      int p1 = cellend[rowbase + cx1];
      for (int p = p0 + lane; p < p1; p += 64) {
        float2 pt = sxy[p];
        float sqj = pt.x * pt.x + pt.y * pt.y;
        float dot = qx * pt.x + qy * pt.y;
        float d2 = fmaxf(qs + sqj - 2.0f * dot, 1e-30f);
        if (d2 < t) {
          int pos = atomicAdd(&s_wcount[wid], 1);
          if (pos < CAPW)
            s_wc[wid][pos] = (((unsigned long long)__float_as_uint(d2)) << 32) |
                             (unsigned long long)(unsigned)sidx[p];
        }
      }
      // overshoot early-exit: true C >= observed C > CAPW keeps bisection bracket valid;
      // successful attempts (C <= CAPW) never trigger this, so their stored set is complete.
      if (s_wcount[wid] > CAPW) break;
    }
    C = s_wcount[wid];  // uniform per wave
    if (C >= KNN && C <= CAPW) break;
    if (C < KNN) {
      tlo = t;
      t = (thi > 0.0f) ? sqrtf(tlo * thi)
                       : fminf(t * fminf(fmaxf(96.0f / (float)(C > 0 ? C : 1), 3.0f), 16.0f), TMAX);
    } else {
      thi = t;
      t = (tlo > 0.0f) ? sqrtf(tlo * thi) : t * fmaxf(64.0f / (float)C, 0.02f);
    }
  }
  if (C > CAPW) C = CAPW;

  // rank-canonical selection (ties -> smaller original idx, == top_k); wave-internal
  for (int c = lane; c < C; c += 64) {
    unsigned long long mine = s_wc[wid][c];
    int rank = 0;
    for (int qq = 0; qq < C; ++qq) rank += (s_wc[wid][qq] < mine) ? 1 : 0;
    if (rank < KNN) {
      s_seld[wid][rank] = __uint_as_float((unsigned)(mine >> 32));
      s_seli[wid][rank] = (int)(unsigned)(mine & 0xffffffffull);
    }
  }
  float w = 0, wy = 0, wm = 0;
  if (lane < KNN) {
    int idx = s_seli[wid][lane];
    float dist = sqrtf(s_seld[wid][lane]);  // == reference sqrt(max(d2,1e-30))
    w = expf(-0.1f * dist);
    wy = w * y[idx];
    wm = w * m[idx];
  }
  for (int off = 32; off > 0; off >>= 1) {
    w  += __shfl_down(w, off, 64);
    wy += __shfl_down(wy, off, 64);
    wm += __shfl_down(wm, off, 64);
  }
  if (lane == 0) {
    double yi = (double)y[iq], mi = (double)m[iq];
    s_part[wid][0] = (double)w;
    s_part[wid][1] = yi * (double)wy;
    s_part[wid][2] = yi * (double)w + (double)wy;
    s_part[wid][3] = mi * (double)wm;
    s_part[wid][4] = mi * (double)w + (double)wm;
  }
  __syncthreads();
  if (tid < 5) {
    double val = s_part[0][tid] + s_part[1][tid] + s_part[2][tid] + s_part[3][tid];
    atomicAdd(&ws[(blockIdx.x & (NSLOT - 1)) * 16 + 4 + tid], val);
  }
}

// fallback (ws too small for grid): one wave per query, full N scan, same settle/rank/accumulate
__global__ __launch_bounds__(BLOCK) void knn_full_kernel(const float4* __restrict__ x4,
                                                         const float* __restrict__ y,
                                                         const float* __restrict__ m,
                                                         double* __restrict__ ws, int N) {
  __shared__ unsigned long long s_wc[4][CAPW];
  __shared__ int s_wcount[4];
  __shared__ float s_seld[4][KNN];
  __shared__ int s_seli[4][KNN];
  __shared__ double s_part[4][5];
  const int tid = threadIdx.x, lane = tid & 63, wid = tid >> 6;
  const int iq = blockIdx.x * 4 + wid;
  double pW = 0, pS1y = 0, pS2y = 0, pS1m = 0, pS2m = 0;
  if (iq < N) {
    float4 qv = x4[iq];
    const float qx = qv.x, qy = qv.y, qs = qx * qx + qy * qy;
    float t = knn_threshold(qs, N);
    float tlo = 0.0f, thi = -1.0f;
    int C = 0;
    for (int att = 0; att < 24; ++att) {
      if (lane == 0) s_wcount[wid] = 0;
      for (int j = lane; j < N; j += 64) {
        float4 pt = x4[j];
        float sqj = pt.x * pt.x + pt.y * pt.y;
        float dot = qx * pt.x + qy * pt.y;
        float d2 = fmaxf(qs + sqj - 2.0f * dot, 1e-30f);
        if (d2 < t) {
          int pos = atomicAdd(&s_wcount[wid], 1);
          if (pos < CAPW)
            s_wc[wid][pos] = (((unsigned long long)__float_as_uint(d2)) << 32) |
                             (unsigned long long)(unsigned)j;
        }
      }
      C = s_wcount[wid];
      if (C >= KNN && C <= CAPW) break;
      if (C < KNN) {
        tlo = t;
        t = (thi > 0.0f) ? sqrtf(tlo * thi)
                         : fminf(t * fminf(fmaxf(96.0f / (float)(C > 0 ? C : 1), 3.0f), 16.0f), TMAX);
      } else {
        thi = t;
        t = (tlo > 0.0f) ? sqrtf(tlo * thi) : t * fmaxf(64.0f / (float)C, 0.02f);
      }
    }
    if (C > CAPW) C = CAPW;
    for (int c = lane; c < C; c += 64) {
      unsigned long long mine = s_wc[wid][c];
      int rank = 0;
      for (int qq = 0; qq < C; ++qq) rank += (s_wc[wid][qq] < mine) ? 1 : 0;
      if (rank < KNN) {
        s_seld[wid][rank] = __uint_as_float((unsigned)(mine >> 32));
        s_seli[wid][rank] = (int)(unsigned)(mine & 0xffffffffull);
      }
    }
    float w = 0, wy = 0, wm = 0;
    if (lane < KNN) {
      int idx = s_seli[wid][lane];
      float dist = sqrtf(s_seld[wid][lane]);
      w = expf(-0.1f * dist);
      wy = w * y[idx];
      wm = w * m[idx];
    }
    for (int off = 32; off > 0; off >>= 1) {
      w  += __shfl_down(w, off, 64);
      wy += __shfl_down(wy, off, 64);
      wm += __shfl_down(wm, off, 64);
    }
    if (lane == 0) {
      double yi = (double)y[iq], mi = (double)m[iq];
      pW = (double)w;
      pS1y = yi * (double)wy;
      pS2y = yi * (double)w + (double)wy;
      pS1m = mi * (double)wm;
      pS2m = mi * (double)w + (double)wm;
    }
  }
  if (lane == 0) {
    s_part[wid][0] = pW; s_part[wid][1] = pS1y; s_part[wid][2] = pS2y;
    s_part[wid][3] = pS1m; s_part[wid][4] = pS2m;
  }
  __syncthreads();
  if (tid < 5) {
    double val = s_part[0][tid] + s_part[1][tid] + s_part[2][tid] + s_part[3][tid];
    atomicAdd(&ws[(blockIdx.x & (NSLOT - 1)) * 16 + 4 + tid], val);
  }
}

__global__ __launch_bounds__(128) void finalize_kernel(const double* __restrict__ ws,
                                                       float* __restrict__ out, int N) {
  __shared__ double part[2][9];
  int tid = threadIdx.x;  // 128 threads = NSLOT
  double v[9];
#pragma unroll
  for (int c = 0; c < 9; ++c) v[c] = ws[tid * 16 + c];
#pragma unroll
  for (int c = 0; c < 9; ++c)
    for (int off = 32; off > 0; off >>= 1) v[c] += __shfl_down(v[c], off, 64);
  if ((tid & 63) == 0)
#pragma unroll
    for (int c = 0; c < 9; ++c) part[tid >> 6][c] = v[c];
  __syncthreads();
  if (tid == 0) {
    double t[9];
#pragma unroll
    for (int c = 0; c < 9; ++c) t[c] = part[0][c] + part[1][c];
    double sy = t[0], sy2 = t[1], sm = t[2], sm2 = t[3];
    double W = t[4], S1y = t[5], S2y = t[6], S1m = t[7], S2m = t[8];
    double muy = sy / (double)N, mum = sm / (double)N;
    double deny = sy2 - sy * sy / (double)N;
    double denm = sm2 - sm * sm / (double)N;
    double numy = S1y - muy * S2y + muy * muy * W;
    double numm = S1m - mum * S2m + mum * mum * W;
    out[0] = (float)((double)N / W * numy / deny);
    out[1] = (float)((double)N / W * numm / denm);
  }
}

extern "C" void kernel_launch(void* const* d_in, const int* in_sizes, int n_in,
                              void* d_out, int out_size, void* d_ws, size_t ws_size,
                              hipStream_t stream) {
  const float4* x4 = (const float4*)d_in[0];  // (1, N, 4)
  const float* y   = (const float*)d_in[1];   // (1, N, 1)
  const float* mu  = (const float*)d_in[2];   // (1, N, 1)
  float* out = (float*)d_out;
  int N = in_sizes[1];  // 12288
  double* ws = (double*)d_ws;

  const size_t slots_b = (size_t)NSLOT * 16 * sizeof(double);          // 16384
  const size_t cells_b = (size_t)NCELL * sizeof(int);                  // 16384
  const size_t sxy_off = slots_b + cells_b;                            // 32768
  const size_t sidx_off = sxy_off + (size_t)N * sizeof(float2);        // 131072
  const size_t full_need = sidx_off + (size_t)N * sizeof(int);         // 180224

  int nblk = (N + BLOCK - 1) / BLOCK;
  if (ws_size >= full_need) {
    int* cellarr = (int*)((char*)d_ws + slots_b);
    float2* sxy = (float2*)((char*)d_ws + sxy_off);
    int* sidx = (int*)((char*)d_ws + sidx_off);
    hipMemsetAsync(d_ws, 0, slots_b + cells_b, stream);
    count_sums_kernel<<<nblk, BLOCK, 0, stream>>>(x4, y, mu, cellarr, ws, N);
    scan_kernel<<<1, BLOCK, 0, stream>>>(cellarr);
    scatter_kernel<<<nblk, BLOCK, 0, stream>>>(x4, cellarr, sxy, sidx, N);
    query_kernel<<<N / 4, BLOCK, 0, stream>>>(cellarr, sxy, sidx, y, mu, ws, N);
  } else {
    hipMemsetAsync(d_ws, 0, slots_b, stream);
    count_sums_kernel<<<nblk, BLOCK, 0, stream>>>(x4, y, mu, nullptr, ws, N);
    knn_full_kernel<<<(N + 3) / 4, BLOCK, 0, stream>>>(x4, y, mu, ws, N);
  }
  finalize_kernel<<<1, 128, 0, stream>>>(ws, out, N);
}

// Round 17
// 75.077 us; speedup vs baseline: 2.8029x; 1.0986x over previous
//
#include <hip/hip_runtime.h>

#define KNN 32
#define BLOCK 256
#define NSLOT 128
#define GC 64
#define NCELL (GC * GC)
#define XMIN (-4.5f)
#define INVCS (64.0f / 9.0f)
#define CAPW 224
#define TGT 48.0f
#define TMAX 160.0f  // > max possible d2 (~155): rad covers whole grid -> count = N

// ws layout (full path, 229376 B):
//   [0, 16384):        NSLOT slots x 16 f64   c=0..3: sum_y,sum_y2,sum_m,sum_m2; c=4..8: W,S1y,S2y,S1m,S2m
//   [16384, 32768):    cellarr[NCELL] int     counts -> exclusive starts -> (after scatter) cell END offsets
//   [32768, 131072):   sorted_xy[N] float2
//   [131072, 180224):  sorted_idx[N] int
//   [180224, 229376):  t_arr[N] float         per-point d2 threshold (original index order)
// moran num_y = S1y - mu_y*S2y + mu_y^2*W  (mean-free expansion; exact in f64)

__device__ inline float bessel_i0f(float z) {
  if (z < 3.75f) {
    float u = z * z * (1.0f / (3.75f * 3.75f));
    return 1.0f + u * (3.5156229f + u * (3.0899424f + u * (1.2067492f +
                  u * (0.2659732f + u * (0.0360768f + u * 0.0045813f)))));
  } else {
    float w = 3.75f / z;
    float p = 0.39894228f + w * (0.01328592f + w * (0.00225319f + w * (-0.00157565f +
              w * (0.00916281f + w * (-0.02057706f + w * (0.02635537f +
              w * (-0.01647633f + w * 0.00392377f)))))));
    return __expf(z) * p * __frsqrt_rn(z);
  }
}

// d2-threshold with E[#points: d2<t] ~= TGT (noncentral chi^2; 16-pt midpoint, 2 fixed-point iters)
__device__ inline float knn_threshold(float qs, int N) {
  float t = fminf(fmaxf((2.0f * TGT / (float)N) * __expf(0.5f * qs), 1e-3f), 12.0f);
  float aq = sqrtf(qs);
#pragma unroll
  for (int nit = 0; nit < 2; ++nit) {
    float dt = t * (1.0f / 16.0f);
    float acc = 0.0f;
#pragma unroll
    for (int k = 0; k < 16; ++k) {
      float s = ((float)k + 0.5f) * dt;
      acc += __expf(-0.5f * s) * bessel_i0f(aq * sqrtf(s));
    }
    float E = 0.5f * (float)N * __expf(-0.5f * qs) * acc * dt;
    t = fminf(fmaxf(t * (TGT / fmaxf(E, 1.0f)), 1e-3f), 32.0f);
  }
  return t;
}

__device__ inline int cell_of(float v) {
  return min(max((int)((v - XMIN) * INVCS), 0), GC - 1);
}

__global__ __launch_bounds__(BLOCK) void thresh_kernel(const float4* __restrict__ x4,
                                                       float* __restrict__ t_arr, int N) {
  int j = blockIdx.x * BLOCK + threadIdx.x;
  if (j < N) {
    float4 xi = x4[j];
    float qs = xi.x * xi.x + xi.y * xi.y;
    t_arr[j] = knn_threshold(qs, N);
  }
}

// counts points per cell (if cellcnt != null) and accumulates global y/m sums into hashed slots
__global__ __launch_bounds__(BLOCK) void count_sums_kernel(const float4* __restrict__ x4,
                                                           const float* __restrict__ y,
                                                           const float* __restrict__ m,
                                                           int* cellcnt, double* __restrict__ ws,
                                                           int N) {
  int tid = threadIdx.x, lane = tid & 63, wid = tid >> 6;
  int j = blockIdx.x * BLOCK + tid;
  double sy = 0, sy2 = 0, sm = 0, sm2 = 0;
  if (j < N) {
    float4 p = x4[j];
    if (cellcnt) atomicAdd(&cellcnt[cell_of(p.y) * GC + cell_of(p.x)], 1);
    sy = (double)y[j]; sy2 = sy * sy;
    sm = (double)m[j]; sm2 = sm * sm;
  }
  for (int off = 32; off > 0; off >>= 1) {
    sy  += __shfl_down(sy, off, 64);
    sy2 += __shfl_down(sy2, off, 64);
    sm  += __shfl_down(sm, off, 64);
    sm2 += __shfl_down(sm2, off, 64);
  }
  __shared__ double red[4][4];
  if (lane == 0) { red[wid][0] = sy; red[wid][1] = sy2; red[wid][2] = sm; red[wid][3] = sm2; }
  __syncthreads();
  if (tid < 4) {
    double v = red[0][tid] + red[1][tid] + red[2][tid] + red[3][tid];
    atomicAdd(&ws[(blockIdx.x & (NSLOT - 1)) * 16 + tid], v);
  }
}

// exclusive scan of NCELL counts in place (one block, 16 cells/thread)
__global__ __launch_bounds__(BLOCK) void scan_kernel(int* cellarr) {
  __shared__ int wtot[4];
  int tid = threadIdx.x, lane = tid & 63, wid = tid >> 6;
  int base = tid * 16;
  int v[16];
  int tot = 0;
#pragma unroll
  for (int k = 0; k < 16; ++k) { v[k] = cellarr[base + k]; tot += v[k]; }
  int scan = tot;
  for (int off = 1; off < 64; off <<= 1) {
    int u = __shfl_up(scan, off, 64);
    if (lane >= off) scan += u;
  }
  if (lane == 63) wtot[wid] = scan;
  __syncthreads();
  int add = 0;
  for (int w = 0; w < wid; ++w) add += wtot[w];
  int excl = add + scan - tot;
#pragma unroll
  for (int k = 0; k < 16; ++k) { int c = v[k]; cellarr[base + k] = excl; excl += c; }
}

// scatter into sorted order; afterwards cellarr[c] == END offset of cell c
__global__ __launch_bounds__(BLOCK) void scatter_kernel(const float4* __restrict__ x4,
                                                        int* cellarr, float2* __restrict__ sxy,
                                                        int* __restrict__ sidx, int N) {
  int j = blockIdx.x * BLOCK + threadIdx.x;
  if (j < N) {
    float4 p = x4[j];
    int pos = atomicAdd(&cellarr[cell_of(p.y) * GC + cell_of(p.x)], 1);
    sxy[pos] = make_float2(p.x, p.y);
    sidx[pos] = j;
  }
}

// ONE WAVE PER QUERY (sorted order -> uniform blocks + L2 locality); ring scan with
// early-exit on overshoot; exact-count verify + geometric-bisection settle.
// Threshold loaded from precomputed t_arr (Bessel model moved off the hot path).
__global__ __launch_bounds__(BLOCK) void query_kernel(const int* __restrict__ cellend,
                                                      const float2* __restrict__ sxy,
                                                      const int* __restrict__ sidx,
                                                      const float* __restrict__ y,
                                                      const float* __restrict__ m,
                                                      const float* __restrict__ t_arr,
                                                      double* __restrict__ ws, int N) {
  __shared__ unsigned long long s_wc[4][CAPW];
  __shared__ int s_wcount[4];
  __shared__ float s_seld[4][KNN];
  __shared__ int s_seli[4][KNN];
  __shared__ double s_part[4][5];

  const int tid = threadIdx.x, lane = tid & 63, wid = tid >> 6;
  const int qi = blockIdx.x * 4 + wid;  // sorted-order query position (N divisible by 4)

  float2 q = sxy[qi];
  const int iq = sidx[qi];
  const float qx = q.x, qy = q.y, qs = qx * qx + qy * qy;
  float t = t_arr ? t_arr[iq] : knn_threshold(qs, N);
  float tlo = 0.0f, thi = -1.0f;
  int C = 0;
  for (int att = 0; att < 24; ++att) {
    if (lane == 0) s_wcount[wid] = 0;  // wave-internal; DS ops in program order
    float rad = sqrtf(t);
    int cx0 = min(max((int)((qx - rad - XMIN) * INVCS), 0), GC - 1);
    int cx1 = min(max((int)((qx + rad - XMIN) * INVCS), 0), GC - 1);
    int cy0 = min(max((int)((qy - rad - XMIN) * INVCS), 0), GC - 1);
    int cy1 = min(max((int)((qy + rad - XMIN) * INVCS), 0), GC - 1);
    for (int cy = cy0; cy <= cy1; ++cy) {
      int rowbase = cy * GC;
      int p0 = (rowbase + cx0) ? cellend[rowbase + cx0 - 1] : 0;
      int p1 = cellend[rowbase + cx1];
      for (int p = p0 + lane; p < p1; p += 64) {
        float2 pt = sxy[p];
        float sqj = pt.x * pt.x + pt.y * pt.y;
        float dot = qx * pt.x + qy * pt.y;
        float d2 = fmaxf(qs + sqj - 2.0f * dot, 1e-30f);
        if (d2 < t) {
          int pos = atomicAdd(&s_wcount[wid], 1);
          if (pos < CAPW)
            s_wc[wid][pos] = (((unsigned long long)__float_as_uint(d2)) << 32) |
                             (unsigned long long)(unsigned)sidx[p];
        }
      }
      // overshoot early-exit: true C >= observed C > CAPW keeps bisection bracket valid;
      // successful attempts (C <= CAPW) never trigger this, so their stored set is complete.
      if (s_wcount[wid] > CAPW) break;
    }
    C = s_wcount[wid];  // uniform per wave
    if (C >= KNN && C <= CAPW) break;
    if (C < KNN) {
      tlo = t;
      t = (thi > 0.0f) ? sqrtf(tlo * thi)
                       : fminf(t * fminf(fmaxf(96.0f / (float)(C > 0 ? C : 1), 3.0f), 16.0f), TMAX);
    } else {
      thi = t;
      t = (tlo > 0.0f) ? sqrtf(tlo * thi) : t * fmaxf(64.0f / (float)C, 0.02f);
    }
  }
  if (C > CAPW) C = CAPW;

  // rank-canonical selection (ties -> smaller original idx, == top_k); wave-internal
  for (int c = lane; c < C; c += 64) {
    unsigned long long mine = s_wc[wid][c];
    int rank = 0;
    for (int qq = 0; qq < C; ++qq) rank += (s_wc[wid][qq] < mine) ? 1 : 0;
    if (rank < KNN) {
      s_seld[wid][rank] = __uint_as_float((unsigned)(mine >> 32));
      s_seli[wid][rank] = (int)(unsigned)(mine & 0xffffffffull);
    }
  }
  float w = 0, wy = 0, wm = 0;
  if (lane < KNN) {
    int idx = s_seli[wid][lane];
    float dist = sqrtf(s_seld[wid][lane]);  // == reference sqrt(max(d2,1e-30))
    w = expf(-0.1f * dist);
    wy = w * y[idx];
    wm = w * m[idx];
  }
  for (int off = 32; off > 0; off >>= 1) {
    w  += __shfl_down(w, off, 64);
    wy += __shfl_down(wy, off, 64);
    wm += __shfl_down(wm, off, 64);
  }
  if (lane == 0) {
    double yi = (double)y[iq], mi = (double)m[iq];
    s_part[wid][0] = (double)w;
    s_part[wid][1] = yi * (double)wy;
    s_part[wid][2] = yi * (double)w + (double)wy;
    s_part[wid][3] = mi * (double)wm;
    s_part[wid][4] = mi * (double)w + (double)wm;
  }
  __syncthreads();
  if (tid < 5) {
    double val = s_part[0][tid] + s_part[1][tid] + s_part[2][tid] + s_part[3][tid];
    atomicAdd(&ws[(blockIdx.x & (NSLOT - 1)) * 16 + 4 + tid], val);
  }
}

// fallback (ws too small for grid): one wave per query, full N scan, same settle/rank/accumulate
__global__ __launch_bounds__(BLOCK) void knn_full_kernel(const float4* __restrict__ x4,
                                                         const float* __restrict__ y,
                                                         const float* __restrict__ m,
                                                         double* __restrict__ ws, int N) {
  __shared__ unsigned long long s_wc[4][CAPW];
  __shared__ int s_wcount[4];
  __shared__ float s_seld[4][KNN];
  __shared__ int s_seli[4][KNN];
  __shared__ double s_part[4][5];
  const int tid = threadIdx.x, lane = tid & 63, wid = tid >> 6;
  const int iq = blockIdx.x * 4 + wid;
  double pW = 0, pS1y = 0, pS2y = 0, pS1m = 0, pS2m = 0;
  if (iq < N) {
    float4 qv = x4[iq];
    const float qx = qv.x, qy = qv.y, qs = qx * qx + qy * qy;
    float t = knn_threshold(qs, N);
    float tlo = 0.0f, thi = -1.0f;
    int C = 0;
    for (int att = 0; att < 24; ++att) {
      if (lane == 0) s_wcount[wid] = 0;
      for (int j = lane; j < N; j += 64) {
        float4 pt = x4[j];
        float sqj = pt.x * pt.x + pt.y * pt.y;
        float dot = qx * pt.x + qy * pt.y;
        float d2 = fmaxf(qs + sqj - 2.0f * dot, 1e-30f);
        if (d2 < t) {
          int pos = atomicAdd(&s_wcount[wid], 1);
          if (pos < CAPW)
            s_wc[wid][pos] = (((unsigned long long)__float_as_uint(d2)) << 32) |
                             (unsigned long long)(unsigned)j;
        }
      }
      C = s_wcount[wid];
      if (C >= KNN && C <= CAPW) break;
      if (C < KNN) {
        tlo = t;
        t = (thi > 0.0f) ? sqrtf(tlo * thi)
                         : fminf(t * fminf(fmaxf(96.0f / (float)(C > 0 ? C : 1), 3.0f), 16.0f), TMAX);
      } else {
        thi = t;
        t = (tlo > 0.0f) ? sqrtf(tlo * thi) : t * fmaxf(64.0f / (float)C, 0.02f);
      }
    }
    if (C > CAPW) C = CAPW;
    for (int c = lane; c < C; c += 64) {
      unsigned long long mine = s_wc[wid][c];
      int rank = 0;
      for (int qq = 0; qq < C; ++qq) rank += (s_wc[wid][qq] < mine) ? 1 : 0;
      if (rank < KNN) {
        s_seld[wid][rank] = __uint_as_float((unsigned)(mine >> 32));
        s_seli[wid][rank] = (int)(unsigned)(mine & 0xffffffffull);
      }
    }
    float w = 0, wy = 0, wm = 0;
    if (lane < KNN) {
      int idx = s_seli[wid][lane];
      float dist = sqrtf(s_seld[wid][lane]);
      w = expf(-0.1f * dist);
      wy = w * y[idx];
      wm = w * m[idx];
    }
    for (int off = 32; off > 0; off >>= 1) {
      w  += __shfl_down(w, off, 64);
      wy += __shfl_down(wy, off, 64);
      wm += __shfl_down(wm, off, 64);
    }
    if (lane == 0) {
      double yi = (double)y[iq], mi = (double)m[iq];
      pW = (double)w;
      pS1y = yi * (double)wy;
      pS2y = yi * (double)w + (double)wy;
      pS1m = mi * (double)wm;
      pS2m = mi * (double)w + (double)wm;
    }
  }
  if (lane == 0) {
    s_part[wid][0] = pW; s_part[wid][1] = pS1y; s_part[wid][2] = pS2y;
    s_part[wid][3] = pS1m; s_part[wid][4] = pS2m;
  }
  __syncthreads();
  if (tid < 5) {
    double val = s_part[0][tid] + s_part[1][tid] + s_part[2][tid] + s_part[3][tid];
    atomicAdd(&ws[(blockIdx.x & (NSLOT - 1)) * 16 + 4 + tid], val);
  }
}

__global__ __launch_bounds__(128) void finalize_kernel(const double* __restrict__ ws,
                                                       float* __restrict__ out, int N) {
  __shared__ double part[2][9];
  int tid = threadIdx.x;  // 128 threads = NSLOT
  double v[9];
#pragma unroll
  for (int c = 0; c < 9; ++c) v[c] = ws[tid * 16 + c];
#pragma unroll
  for (int c = 0; c < 9; ++c)
    for (int off = 32; off > 0; off >>= 1) v[c] += __shfl_down(v[c], off, 64);
  if ((tid & 63) == 0)
#pragma unroll
    for (int c = 0; c < 9; ++c) part[tid >> 6][c] = v[c];
  __syncthreads();
  if (tid == 0) {
    double t[9];
#pragma unroll
    for (int c = 0; c < 9; ++c) t[c] = part[0][c] + part[1][c];
    double sy = t[0], sy2 = t[1], sm = t[2], sm2 = t[3];
    double W = t[4], S1y = t[5], S2y = t[6], S1m = t[7], S2m = t[8];
    double muy = sy / (double)N, mum = sm / (double)N;
    double deny = sy2 - sy * sy / (double)N;
    double denm = sm2 - sm * sm / (double)N;
    double numy = S1y - muy * S2y + muy * muy * W;
    double numm = S1m - mum * S2m + mum * mum * W;
    out[0] = (float)((double)N / W * numy / deny);
    out[1] = (float)((double)N / W * numm / denm);
  }
}

extern "C" void kernel_launch(void* const* d_in, const int* in_sizes, int n_in,
                              void* d_out, int out_size, void* d_ws, size_t ws_size,
                              hipStream_t stream) {
  const float4* x4 = (const float4*)d_in[0];  // (1, N, 4)
  const float* y   = (const float*)d_in[1];   // (1, N, 1)
  const float* mu  = (const float*)d_in[2];   // (1, N, 1)
  float* out = (float*)d_out;
  int N = in_sizes[1];  // 12288
  double* ws = (double*)d_ws;

  const size_t slots_b = (size_t)NSLOT * 16 * sizeof(double);          // 16384
  const size_t cells_b = (size_t)NCELL * sizeof(int);                  // 16384
  const size_t sxy_off = slots_b + cells_b;                            // 32768
  const size_t sidx_off = sxy_off + (size_t)N * sizeof(float2);        // 131072
  const size_t t_off = sidx_off + (size_t)N * sizeof(int);             // 180224
  const size_t grid_need = t_off;
  const size_t t_need = t_off + (size_t)N * sizeof(float);             // 229376

  int nblk = (N + BLOCK - 1) / BLOCK;
  if (ws_size >= grid_need) {
    int* cellarr = (int*)((char*)d_ws + slots_b);
    float2* sxy = (float2*)((char*)d_ws + sxy_off);
    int* sidx = (int*)((char*)d_ws + sidx_off);
    float* t_arr = (ws_size >= t_need) ? (float*)((char*)d_ws + t_off) : nullptr;
    hipMemsetAsync(d_ws, 0, slots_b + cells_b, stream);
    count_sums_kernel<<<nblk, BLOCK, 0, stream>>>(x4, y, mu, cellarr, ws, N);
    if (t_arr) thresh_kernel<<<nblk, BLOCK, 0, stream>>>(x4, t_arr, N);
    scan_kernel<<<1, BLOCK, 0, stream>>>(cellarr);
    scatter_kernel<<<nblk, BLOCK, 0, stream>>>(x4, cellarr, sxy, sidx, N);
    query_kernel<<<N / 4, BLOCK, 0, stream>>>(cellarr, sxy, sidx, y, mu, t_arr, ws, N);
  } else {
    hipMemsetAsync(d_ws, 0, slots_b, stream);
    count_sums_kernel<<<nblk, BLOCK, 0, stream>>>(x4, y, mu, nullptr, ws, N);
    knn_full_kernel<<<(N + 3) / 4, BLOCK, 0, stream>>>(x4, y, mu, ws, N);
  }
  finalize_kernel<<<1, 128, 0, stream>>>(ws, out, N);
}

// Round 18
// 74.811 us; speedup vs baseline: 2.8128x; 1.0035x over previous
//
#include <hip/hip_runtime.h>

#define KNN 32
#define BLOCK 256
#define NSLOT 128
#define GC 64
#define NCELL (GC * GC)
#define XMIN (-4.5f)
#define INVCS (64.0f / 9.0f)
#define CAPW 224
#define TGT 48.0f
#define TMAX 160.0f  // > max possible d2 (~155): rad covers whole grid -> count = N

// ws layout (full path, 229376 B):
//   [0, 16384):        NSLOT slots x 16 f64   c=0..3: sum_y,sum_y2,sum_m,sum_m2; c=4..8: W,S1y,S2y,S1m,S2m
//   [16384, 32768):    cellarr[NCELL] int     counts -> exclusive starts -> (after scatter) cell END offsets
//   [32768, 131072):   sorted_xy[N] float2
//   [131072, 180224):  sorted_idx[N] int
//   [180224, 229376):  t_arr[N] float         per-point d2 threshold (original index order)
// moran num_y = S1y - mu_y*S2y + mu_y^2*W  (mean-free expansion; exact in f64)

__device__ inline float bessel_i0f(float z) {
  if (z < 3.75f) {
    float u = z * z * (1.0f / (3.75f * 3.75f));
    return 1.0f + u * (3.5156229f + u * (3.0899424f + u * (1.2067492f +
                  u * (0.2659732f + u * (0.0360768f + u * 0.0045813f)))));
  } else {
    float w = 3.75f / z;
    float p = 0.39894228f + w * (0.01328592f + w * (0.00225319f + w * (-0.00157565f +
              w * (0.00916281f + w * (-0.02057706f + w * (0.02635537f +
              w * (-0.01647633f + w * 0.00392377f)))))));
    return __expf(z) * p * __frsqrt_rn(z);
  }
}

// d2-threshold with E[#points: d2<t] ~= TGT (noncentral chi^2; 16-pt midpoint, 2 fixed-point iters)
__device__ inline float knn_threshold(float qs, int N) {
  float t = fminf(fmaxf((2.0f * TGT / (float)N) * __expf(0.5f * qs), 1e-3f), 12.0f);
  float aq = sqrtf(qs);
#pragma unroll
  for (int nit = 0; nit < 2; ++nit) {
    float dt = t * (1.0f / 16.0f);
    float acc = 0.0f;
#pragma unroll
    for (int k = 0; k < 16; ++k) {
      float s = ((float)k + 0.5f) * dt;
      acc += __expf(-0.5f * s) * bessel_i0f(aq * sqrtf(s));
    }
    float E = 0.5f * (float)N * __expf(-0.5f * qs) * acc * dt;
    t = fminf(fmaxf(t * (TGT / fmaxf(E, 1.0f)), 1e-3f), 32.0f);
  }
  return t;
}

__device__ inline int cell_of(float v) {
  return min(max((int)((v - XMIN) * INVCS), 0), GC - 1);
}

// merged prep: per-cell counts + per-point threshold + global y/m sums (one x4/y/m read)
__global__ __launch_bounds__(BLOCK) void prep_kernel(const float4* __restrict__ x4,
                                                     const float* __restrict__ y,
                                                     const float* __restrict__ m,
                                                     int* cellcnt, float* __restrict__ t_arr,
                                                     double* __restrict__ ws, int N) {
  int tid = threadIdx.x, lane = tid & 63, wid = tid >> 6;
  int j = blockIdx.x * BLOCK + tid;
  double sy = 0, sy2 = 0, sm = 0, sm2 = 0;
  if (j < N) {
    float4 p = x4[j];
    if (cellcnt) atomicAdd(&cellcnt[cell_of(p.y) * GC + cell_of(p.x)], 1);
    float qs = p.x * p.x + p.y * p.y;
    if (t_arr) t_arr[j] = knn_threshold(qs, N);
    sy = (double)y[j]; sy2 = sy * sy;
    sm = (double)m[j]; sm2 = sm * sm;
  }
  for (int off = 32; off > 0; off >>= 1) {
    sy  += __shfl_down(sy, off, 64);
    sy2 += __shfl_down(sy2, off, 64);
    sm  += __shfl_down(sm, off, 64);
    sm2 += __shfl_down(sm2, off, 64);
  }
  __shared__ double red[4][4];
  if (lane == 0) { red[wid][0] = sy; red[wid][1] = sy2; red[wid][2] = sm; red[wid][3] = sm2; }
  __syncthreads();
  if (tid < 4) {
    double v = red[0][tid] + red[1][tid] + red[2][tid] + red[3][tid];
    atomicAdd(&ws[(blockIdx.x & (NSLOT - 1)) * 16 + tid], v);
  }
}

// exclusive scan of NCELL counts in place (one block, 16 cells/thread)
__global__ __launch_bounds__(BLOCK) void scan_kernel(int* cellarr) {
  __shared__ int wtot[4];
  int tid = threadIdx.x, lane = tid & 63, wid = tid >> 6;
  int base = tid * 16;
  int v[16];
  int tot = 0;
#pragma unroll
  for (int k = 0; k < 16; ++k) { v[k] = cellarr[base + k]; tot += v[k]; }
  int scan = tot;
  for (int off = 1; off < 64; off <<= 1) {
    int u = __shfl_up(scan, off, 64);
    if (lane >= off) scan += u;
  }
  if (lane == 63) wtot[wid] = scan;
  __syncthreads();
  int add = 0;
  for (int w = 0; w < wid; ++w) add += wtot[w];
  int excl = add + scan - tot;
#pragma unroll
  for (int k = 0; k < 16; ++k) { int c = v[k]; cellarr[base + k] = excl; excl += c; }
}

// scatter into sorted order; afterwards cellarr[c] == END offset of cell c
__global__ __launch_bounds__(BLOCK) void scatter_kernel(const float4* __restrict__ x4,
                                                        int* cellarr, float2* __restrict__ sxy,
                                                        int* __restrict__ sidx, int N) {
  int j = blockIdx.x * BLOCK + threadIdx.x;
  if (j < N) {
    float4 p = x4[j];
    int pos = atomicAdd(&cellarr[cell_of(p.y) * GC + cell_of(p.x)], 1);
    sxy[pos] = make_float2(p.x, p.y);
    sidx[pos] = j;
  }
}

// ONE WAVE PER QUERY; ring scan unrolled x2 (4 loads in flight), sidx hoisted out of the
// push branch; early-exit on overshoot; exact-count verify + geometric-bisection settle.
__global__ __launch_bounds__(BLOCK) void query_kernel(const int* __restrict__ cellend,
                                                      const float2* __restrict__ sxy,
                                                      const int* __restrict__ sidx,
                                                      const float* __restrict__ y,
                                                      const float* __restrict__ m,
                                                      const float* __restrict__ t_arr,
                                                      double* __restrict__ ws, int N) {
  __shared__ unsigned long long s_wc[4][CAPW];
  __shared__ int s_wcount[4];
  __shared__ float s_seld[4][KNN];
  __shared__ int s_seli[4][KNN];
  __shared__ double s_part[4][5];

  const int tid = threadIdx.x, lane = tid & 63, wid = tid >> 6;
  const int qi = blockIdx.x * 4 + wid;  // sorted-order query position (N divisible by 4)

  float2 q = sxy[qi];
  const int iq = sidx[qi];
  const float qx = q.x, qy = q.y, qs = qx * qx + qy * qy;
  float t = t_arr ? t_arr[iq] : knn_threshold(qs, N);
  float tlo = 0.0f, thi = -1.0f;
  int C = 0;
  for (int att = 0; att < 24; ++att) {
    if (lane == 0) s_wcount[wid] = 0;  // wave-internal; DS ops in program order
    float rad = sqrtf(t);
    int cx0 = min(max((int)((qx - rad - XMIN) * INVCS), 0), GC - 1);
    int cx1 = min(max((int)((qx + rad - XMIN) * INVCS), 0), GC - 1);
    int cy0 = min(max((int)((qy - rad - XMIN) * INVCS), 0), GC - 1);
    int cy1 = min(max((int)((qy + rad - XMIN) * INVCS), 0), GC - 1);
    for (int cy = cy0; cy <= cy1; ++cy) {
      int rowbase = cy * GC;
      int p0 = (rowbase + cx0) ? cellend[rowbase + cx0 - 1] : 0;
      int p1 = cellend[rowbase + cx1];
      for (int p = p0 + lane; p < p1; p += 128) {
        int pB = p + 64;
        int pBc = (pB < p1) ? pB : p;  // clamped in-bounds
        // 4 independent loads issue together (all L2-hot)
        float2 ptA = sxy[p];
        float2 ptB = sxy[pBc];
        int siA = sidx[p];
        int siB = sidx[pBc];
        float d2A = fmaxf(qs + (ptA.x * ptA.x + ptA.y * ptA.y) - 2.0f * (qx * ptA.x + qy * ptA.y),
                          1e-30f);
        float d2B = fmaxf(qs + (ptB.x * ptB.x + ptB.y * ptB.y) - 2.0f * (qx * ptB.x + qy * ptB.y),
                          1e-30f);
        if (d2A < t) {
          int pos = atomicAdd(&s_wcount[wid], 1);
          if (pos < CAPW)
            s_wc[wid][pos] = (((unsigned long long)__float_as_uint(d2A)) << 32) |
                             (unsigned long long)(unsigned)siA;
        }
        if (pB < p1 && d2B < t) {
          int pos = atomicAdd(&s_wcount[wid], 1);
          if (pos < CAPW)
            s_wc[wid][pos] = (((unsigned long long)__float_as_uint(d2B)) << 32) |
                             (unsigned long long)(unsigned)siB;
        }
      }
      // overshoot early-exit: true C >= observed C > CAPW keeps bisection bracket valid;
      // successful attempts (C <= CAPW) never trigger this, so their stored set is complete.
      if (s_wcount[wid] > CAPW) break;
    }
    C = s_wcount[wid];  // uniform per wave
    if (C >= KNN && C <= CAPW) break;
    if (C < KNN) {
      tlo = t;
      t = (thi > 0.0f) ? sqrtf(tlo * thi)
                       : fminf(t * fminf(fmaxf(96.0f / (float)(C > 0 ? C : 1), 3.0f), 16.0f), TMAX);
    } else {
      thi = t;
      t = (tlo > 0.0f) ? sqrtf(tlo * thi) : t * fmaxf(64.0f / (float)C, 0.02f);
    }
  }
  if (C > CAPW) C = CAPW;

  // rank-canonical selection (ties -> smaller original idx, == top_k); wave-internal
  for (int c = lane; c < C; c += 64) {
    unsigned long long mine = s_wc[wid][c];
    int rank = 0;
    for (int qq = 0; qq < C; ++qq) rank += (s_wc[wid][qq] < mine) ? 1 : 0;
    if (rank < KNN) {
      s_seld[wid][rank] = __uint_as_float((unsigned)(mine >> 32));
      s_seli[wid][rank] = (int)(unsigned)(mine & 0xffffffffull);
    }
  }
  float w = 0, wy = 0, wm = 0;
  if (lane < KNN) {
    int idx = s_seli[wid][lane];
    float dist = sqrtf(s_seld[wid][lane]);  // == reference sqrt(max(d2,1e-30))
    w = expf(-0.1f * dist);
    wy = w * y[idx];
    wm = w * m[idx];
  }
  for (int off = 32; off > 0; off >>= 1) {
    w  += __shfl_down(w, off, 64);
    wy += __shfl_down(wy, off, 64);
    wm += __shfl_down(wm, off, 64);
  }
  if (lane == 0) {
    double yi = (double)y[iq], mi = (double)m[iq];
    s_part[wid][0] = (double)w;
    s_part[wid][1] = yi * (double)wy;
    s_part[wid][2] = yi * (double)w + (double)wy;
    s_part[wid][3] = mi * (double)wm;
    s_part[wid][4] = mi * (double)w + (double)wm;
  }
  __syncthreads();
  if (tid < 5) {
    double val = s_part[0][tid] + s_part[1][tid] + s_part[2][tid] + s_part[3][tid];
    atomicAdd(&ws[(blockIdx.x & (NSLOT - 1)) * 16 + 4 + tid], val);
  }
}

// fallback (ws too small for grid): one wave per query, full N scan, same settle/rank/accumulate
__global__ __launch_bounds__(BLOCK) void knn_full_kernel(const float4* __restrict__ x4,
                                                         const float* __restrict__ y,
                                                         const float* __restrict__ m,
                                                         double* __restrict__ ws, int N) {
  __shared__ unsigned long long s_wc[4][CAPW];
  __shared__ int s_wcount[4];
  __shared__ float s_seld[4][KNN];
  __shared__ int s_seli[4][KNN];
  __shared__ double s_part[4][5];
  const int tid = threadIdx.x, lane = tid & 63, wid = tid >> 6;
  const int iq = blockIdx.x * 4 + wid;
  double pW = 0, pS1y = 0, pS2y = 0, pS1m = 0, pS2m = 0;
  if (iq < N) {
    float4 qv = x4[iq];
    const float qx = qv.x, qy = qv.y, qs = qx * qx + qy * qy;
    float t = knn_threshold(qs, N);
    float tlo = 0.0f, thi = -1.0f;
    int C = 0;
    for (int att = 0; att < 24; ++att) {
      if (lane == 0) s_wcount[wid] = 0;
      for (int j = lane; j < N; j += 64) {
        float4 pt = x4[j];
        float sqj = pt.x * pt.x + pt.y * pt.y;
        float dot = qx * pt.x + qy * pt.y;
        float d2 = fmaxf(qs + sqj - 2.0f * dot, 1e-30f);
        if (d2 < t) {
          int pos = atomicAdd(&s_wcount[wid], 1);
          if (pos < CAPW)
            s_wc[wid][pos] = (((unsigned long long)__float_as_uint(d2)) << 32) |
                             (unsigned long long)(unsigned)j;
        }
      }
      C = s_wcount[wid];
      if (C >= KNN && C <= CAPW) break;
      if (C < KNN) {
        tlo = t;
        t = (thi > 0.0f) ? sqrtf(tlo * thi)
                         : fminf(t * fminf(fmaxf(96.0f / (float)(C > 0 ? C : 1), 3.0f), 16.0f), TMAX);
      } else {
        thi = t;
        t = (tlo > 0.0f) ? sqrtf(tlo * thi) : t * fmaxf(64.0f / (float)C, 0.02f);
      }
    }
    if (C > CAPW) C = CAPW;
    for (int c = lane; c < C; c += 64) {
      unsigned long long mine = s_wc[wid][c];
      int rank = 0;
      for (int qq = 0; qq < C; ++qq) rank += (s_wc[wid][qq] < mine) ? 1 : 0;
      if (rank < KNN) {
        s_seld[wid][rank] = __uint_as_float((unsigned)(mine >> 32));
        s_seli[wid][rank] = (int)(unsigned)(mine & 0xffffffffull);
      }
    }
    float w = 0, wy = 0, wm = 0;
    if (lane < KNN) {
      int idx = s_seli[wid][lane];
      float dist = sqrtf(s_seld[wid][lane]);
      w = expf(-0.1f * dist);
      wy = w * y[idx];
      wm = w * m[idx];
    }
    for (int off = 32; off > 0; off >>= 1) {
      w  += __shfl_down(w, off, 64);
      wy += __shfl_down(wy, off, 64);
      wm += __shfl_down(wm, off, 64);
    }
    if (lane == 0) {
      double yi = (double)y[iq], mi = (double)m[iq];
      pW = (double)w;
      pS1y = yi * (double)wy;
      pS2y = yi * (double)w + (double)wy;
      pS1m = mi * (double)wm;
      pS2m = mi * (double)w + (double)wm;
    }
  }
  if (lane == 0) {
    s_part[wid][0] = pW; s_part[wid][1] = pS1y; s_part[wid][2] = pS2y;
    s_part[wid][3] = pS1m; s_part[wid][4] = pS2m;
  }
  __syncthreads();
  if (tid < 5) {
    double val = s_part[0][tid] + s_part[1][tid] + s_part[2][tid] + s_part[3][tid];
    atomicAdd(&ws[(blockIdx.x & (NSLOT - 1)) * 16 + 4 + tid], val);
  }
}

__global__ __launch_bounds__(128) void finalize_kernel(const double* __restrict__ ws,
                                                       float* __restrict__ out, int N) {
  __shared__ double part[2][9];
  int tid = threadIdx.x;  // 128 threads = NSLOT
  double v[9];
#pragma unroll
  for (int c = 0; c < 9; ++c) v[c] = ws[tid * 16 + c];
#pragma unroll
  for (int c = 0; c < 9; ++c)
    for (int off = 32; off > 0; off >>= 1) v[c] += __shfl_down(v[c], off, 64);
  if ((tid & 63) == 0)
#pragma unroll
    for (int c = 0; c < 9; ++c) part[tid >> 6][c] = v[c];
  __syncthreads();
  if (tid == 0) {
    double t[9];
#pragma unroll
    for (int c = 0; c < 9; ++c) t[c] = part[0][c] + part[1][c];
    double sy = t[0], sy2 = t[1], sm = t[2], sm2 = t[3];
    double W = t[4], S1y = t[5], S2y = t[6], S1m = t[7], S2m = t[8];
    double muy = sy / (double)N, mum = sm / (double)N;
    double deny = sy2 - sy * sy / (double)N;
    double denm = sm2 - sm * sm / (double)N;
    double numy = S1y - muy * S2y + muy * muy * W;
    double numm = S1m - mum * S2m + mum * mum * W;
    out[0] = (float)((double)N / W * numy / deny);
    out[1] = (float)((double)N / W * numm / denm);
  }
}

extern "C" void kernel_launch(void* const* d_in, const int* in_sizes, int n_in,
                              void* d_out, int out_size, void* d_ws, size_t ws_size,
                              hipStream_t stream) {
  const float4* x4 = (const float4*)d_in[0];  // (1, N, 4)
  const float* y   = (const float*)d_in[1];   // (1, N, 1)
  const float* mu  = (const float*)d_in[2];   // (1, N, 1)
  float* out = (float*)d_out;
  int N = in_sizes[1];  // 12288
  double* ws = (double*)d_ws;

  const size_t slots_b = (size_t)NSLOT * 16 * sizeof(double);          // 16384
  const size_t cells_b = (size_t)NCELL * sizeof(int);                  // 16384
  const size_t sxy_off = slots_b + cells_b;                            // 32768
  const size_t sidx_off = sxy_off + (size_t)N * sizeof(float2);        // 131072
  const size_t t_off = sidx_off + (size_t)N * sizeof(int);             // 180224
  const size_t grid_need = t_off;
  const size_t t_need = t_off + (size_t)N * sizeof(float);             // 229376

  int nblk = (N + BLOCK - 1) / BLOCK;
  if (ws_size >= grid_need) {
    int* cellarr = (int*)((char*)d_ws + slots_b);
    float2* sxy = (float2*)((char*)d_ws + sxy_off);
    int* sidx = (int*)((char*)d_ws + sidx_off);
    float* t_arr = (ws_size >= t_need) ? (float*)((char*)d_ws + t_off) : nullptr;
    hipMemsetAsync(d_ws, 0, slots_b + cells_b, stream);
    prep_kernel<<<nblk, BLOCK, 0, stream>>>(x4, y, mu, cellarr, t_arr, ws, N);
    scan_kernel<<<1, BLOCK, 0, stream>>>(cellarr);
    scatter_kernel<<<nblk, BLOCK, 0, stream>>>(x4, cellarr, sxy, sidx, N);
    query_kernel<<<N / 4, BLOCK, 0, stream>>>(cellarr, sxy, sidx, y, mu, t_arr, ws, N);
  } else {
    hipMemsetAsync(d_ws, 0, slots_b, stream);
    prep_kernel<<<nblk, BLOCK, 0, stream>>>(x4, y, mu, nullptr, nullptr, ws, N);
    knn_full_kernel<<<(N + 3) / 4, BLOCK, 0, stream>>>(x4, y, mu, ws, N);
  }
  finalize_kernel<<<1, 128, 0, stream>>>(ws, out, N);
}